// Round 5
// baseline (121.905 us; speedup 1.0000x reference)
//
#include <hip/hip_runtime.h>
#include <hip/hip_bf16.h>

// Problem constants (match reference)
constexpr int BB = 16384;   // batch
constexpr int CC = 2048;    // classes
constexpr int DD = 256;     // dim
constexpr float THR   = 0.8f;
constexpr float EPSN  = 1e-8f;

typedef __bf16 bf16x8 __attribute__((ext_vector_type(8)));
typedef float  f32x4  __attribute__((ext_vector_type(4)));

// ---------------- workspace layout (bytes) ----------------
// [0)         cnt     : C*4   = 8,192      (zeroed each launch)
// [8,192)     Ecnt    : 4 (pad to 8,256)   (zeroed)
// [8,256)     cls     : B*4   = 65,536
// [73,792)    rowlist : C*64*4 = 524,288   (slot-guarded, no zero needed)
// [598,080)   exists  : C*4   = 8,192
// [606,272)   pn      : B*D*2 = 8,388,608  (bf16)
// [8,994,880) cn      : C*D*2 = 1,048,576  (bf16)
constexpr int ROWSLOTS = 64;  // 2x Poisson(8) max over 2048 classes << 64

// MEASUREMENT NOTE (round 5): k_scan is launched TWICE. It is idempotent in
// effect: cls rewritten with identical values; cnt doubles but k_cn computes
// mean = (2*sum)/(2*n) = sum/n exactly; rowlist slots [0,2n) all written this
// launch; exists/Ecnt unchanged. Total_r5 - Total_r4 ~= scan duration.
__global__ __launch_bounds__(256) void k_scan(const float* __restrict__ labels,
                                              int* __restrict__ cls,
                                              int* __restrict__ cnt,
                                              int* __restrict__ rowlist,
                                              float* __restrict__ out) {
  if (blockIdx.x == 0 && threadIdx.x == 0) *out = 0.f;
  constexpr size_t total = (size_t)BB * CC / 4;
  size_t q = (size_t)blockIdx.x * 256 + threadIdx.x;
  const float4* l4 = reinterpret_cast<const float4*>(labels);
  for (; q < total; q += 2048 * 256) {
    float4 v = l4[q];
    if (v.x >= THR || v.y >= THR || v.z >= THR || v.w >= THR) {
      int f = (int)(q * 4);
      int row = f >> 11;      // / CC
      int col = f & (CC - 1);
      int c = col + (v.x >= THR ? 0 : v.y >= THR ? 1 : v.z >= THR ? 2 : 3);
      cls[row] = c;
      int s = atomicAdd(&cnt[c], 1);
      if (s < ROWSLOTS) rowlist[c * ROWSLOTS + s] = row;
    }
  }
}

// pn = normalize(preds) stored bf16. One wave per row.
__global__ __launch_bounds__(256) void k_pn(const float* __restrict__ preds,
                                            unsigned short* __restrict__ pn) {
  int b = blockIdx.x * 4 + (threadIdx.x >> 6);
  int lane = threadIdx.x & 63;
  float4 v = reinterpret_cast<const float4*>(preds + (size_t)b * DD)[lane];
  float s = v.x * v.x + v.y * v.y + v.z * v.z + v.w * v.w;
#pragma unroll
  for (int o = 32; o > 0; o >>= 1) s += __shfl_xor(s, o);
  float inv = 1.0f / fmaxf(sqrtf(s), EPSN);
  union { ushort4 u4; unsigned short us[4]; } o;
  float f0 = v.x * inv, f1 = v.y * inv, f2 = v.z * inv, f3 = v.w * inv;
  __bf16 h0 = (__bf16)f0, h1 = (__bf16)f1, h2 = (__bf16)f2, h3 = (__bf16)f3;
  o.us[0] = *reinterpret_cast<unsigned short*>(&h0);
  o.us[1] = *reinterpret_cast<unsigned short*>(&h1);
  o.us[2] = *reinterpret_cast<unsigned short*>(&h2);
  o.us[3] = *reinterpret_cast<unsigned short*>(&h3);
  reinterpret_cast<ushort4*>(pn + (size_t)b * DD)[lane] = o.u4;
}

// Per-class: gather rows via rowlist, mean, normalize -> cn bf16 + exists/Ecnt.
__global__ __launch_bounds__(256) void k_cn(
    const float* __restrict__ preds, const int* __restrict__ cnt,
    const int* __restrict__ rowlist, unsigned short* __restrict__ cn,
    int* __restrict__ exists, int* __restrict__ Ecnt) {
  int c = blockIdx.x;
  int t = threadIdx.x;
  int n = cnt[c];
  int nn = n < ROWSLOTS ? n : ROWSLOTS;
  float sum = 0.f;
  for (int i = 0; i < nn; ++i) {
    int row = rowlist[c * ROWSLOTS + i];
    sum += preds[(size_t)row * DD + t];
  }
  float mean = sum / (float)(n > 0 ? n : 1);
  float s = mean * mean;
#pragma unroll
  for (int o = 32; o > 0; o >>= 1) s += __shfl_xor(s, o);
  __shared__ float red[4];
  int wave = t >> 6, lane = t & 63;
  if (lane == 0) red[wave] = s;
  __syncthreads();
  float tot = red[0] + red[1] + red[2] + red[3];
  float inv = 1.0f / fmaxf(sqrtf(tot), EPSN);
  __bf16 h = (__bf16)(mean * inv);
  cn[c * DD + t] = *reinterpret_cast<unsigned short*>(&h);
  if (t == 0) {
    exists[c] = (n > 0) ? 1 : 0;
    if (n > 0) atomicAdd(Ecnt, 1);
  }
}

// ---- k_loss: 256x256 tile, BK=64, 8 waves, dbuf 128KB LDS.
// Round-5 change (T4): counted vmcnt(8) instead of full-drain __syncthreads —
// prev stage's 8 loads are the oldest outstanding; next stage's 8 stay in
// flight across the barrier. setprio(1) around the MFMA cluster (T5).
// Swizzle (rule #21, both-sides, conflict-free r2-r4): element (row,kb) at
// byte row*128 + (kb ^ ((row&7)<<4)); gload_lds dest linear, SOURCE
// inverse-permuted, ds_read same XOR.

__device__ __forceinline__ void stage32k(char* lds, const char* gsrc_row0,
                                         int tid, int ksbyte) {
#pragma unroll
  for (int i = 0; i < 4; ++i) {
    int L = i * 8192 + tid * 16;             // linear LDS byte (32KB / 512thr)
    int row = L >> 7;                        // 128B per row (64 k * 2B)
    int kb  = (L & 127) ^ ((row & 7) << 4);  // involution
    const char* g = gsrc_row0 + (size_t)row * (DD * 2) + ksbyte + kb;
    __builtin_amdgcn_global_load_lds(
        (const __attribute__((address_space(1))) unsigned int*)g,
        (__attribute__((address_space(3))) unsigned int*)(lds + L), 16, 0, 0);
  }
}

__device__ __forceinline__ bf16x8 ldfrag(const char* buf, int row, int kb) {
  return *reinterpret_cast<const bf16x8*>(buf + row * 128 + (kb ^ ((row & 7) << 4)));
}

__global__ __launch_bounds__(512, 2) void k_loss(
    const unsigned short* __restrict__ pn, const unsigned short* __restrict__ cn,
    const int* __restrict__ cls, const int* __restrict__ exists,
    const int* __restrict__ Ecnt, float* __restrict__ out) {
  constexpr int BM = 256, BN = 256;
  __shared__ __align__(16) char sA[2][BM * 64 * 2];   // 2 x 32KB
  __shared__ __align__(16) char sB[2][BN * 64 * 2];   // 2 x 32KB
  __shared__ float red[8];

  // 512 blocks = 64 mtiles x 8 ntiles; bijective XCD swizzle (512 % 8 == 0).
  int bid = blockIdx.x;
  int nb = (bid & 7) * 64 + (bid >> 3);
  int mtile = nb & 63;
  int ntile = nb >> 6;
  int rowbase = mtile * BM, colbase = ntile * BN;
  int tid = threadIdx.x, w = tid >> 6, lane = tid & 63;
  int wm = w >> 2, wn = w & 3;            // wave grid 2 x 4
  int r16 = lane & 15, khi = lane >> 4;   // khi in 0..3
  int arow0 = wm * 128 + r16;             // LDS-A row base for a-frags
  int brow0 = wn * 64 + r16;              // LDS-B row base for b-frags

  const char* pnB = (const char*)pn + (size_t)rowbase * (DD * 2);
  const char* cnB = (const char*)cn + (size_t)colbase * (DD * 2);

  f32x4 acc[8][4];
#pragma unroll
  for (int m = 0; m < 8; ++m)
#pragma unroll
    for (int n = 0; n < 4; ++n) acc[m][n] = {0.f, 0.f, 0.f, 0.f};

  // prologue: stage K-step 0 (8 loads/thread)
  stage32k(sA[0], pnB, tid, 0);
  stage32k(sB[0], cnB, tid, 0);

  int cur = 0;
#pragma unroll
  for (int ks = 0; ks < 4; ++ks) {        // 256 / BK = 4 K-steps
    if (ks < 3) {                         // issue next stage (8 loads/thread)
      stage32k(sA[cur ^ 1], pnB, tid, (ks + 1) * 128);
      stage32k(sB[cur ^ 1], cnB, tid, (ks + 1) * 128);
      asm volatile("s_waitcnt vmcnt(8)" ::: "memory");  // oldest 8 = buf[cur]
    } else {
      asm volatile("s_waitcnt vmcnt(0)" ::: "memory");  // last step: drain
    }
    __builtin_amdgcn_sched_barrier(0);
    __builtin_amdgcn_s_barrier();         // buf[cur] visible to all waves

    const char* bufA = sA[cur];
    const char* bufB = sB[cur];
    __builtin_amdgcn_s_setprio(1);
#pragma unroll
    for (int kk = 0; kk < 2; ++kk) {      // 2 x K=32 per BK=64
      int kb = kk * 64 + khi * 16;
      bf16x8 b[4];
#pragma unroll
      for (int n = 0; n < 4; ++n) b[n] = ldfrag(bufB, brow0 + n * 16, kb);
#pragma unroll
      for (int m = 0; m < 8; ++m) {
        bf16x8 a = ldfrag(bufA, arow0 + m * 16, kb);
#pragma unroll
        for (int n = 0; n < 4; ++n)
          acc[m][n] = __builtin_amdgcn_mfma_f32_16x16x32_bf16(a, b[n], acc[m][n], 0, 0, 0);
      }
    }
    __builtin_amdgcn_s_setprio(0);
    __builtin_amdgcn_s_barrier();         // all reads of buf[cur] retired
    cur ^= 1;                             // before anyone overwrites it
  }

  // Epilogue: pos (diagonal) + hinge neg -> scalar atomic.
  // D layout: col = lane&15, row = (lane>>4)*4 + reg  (m89-verified)
  int E = *Ecnt;
  float inv_B = 1.0f / (float)BB;
  float inv_neg = inv_B / (float)((E - 1) > 0 ? (E - 1) : 1);
  int grow0 = rowbase + wm * 128;

  int clsr[8][4];
#pragma unroll
  for (int m = 0; m < 8; ++m)
#pragma unroll
    for (int r = 0; r < 4; ++r) clsr[m][r] = cls[grow0 + m * 16 + khi * 4 + r];
  int exs[4];
#pragma unroll
  for (int n = 0; n < 4; ++n) exs[n] = exists[colbase + wn * 64 + n * 16 + r16];

  float local = 0.f;
#pragma unroll
  for (int m = 0; m < 8; ++m)
#pragma unroll
    for (int n = 0; n < 4; ++n) {
      int ccol = colbase + wn * 64 + n * 16 + r16;
#pragma unroll
      for (int r = 0; r < 4; ++r) {
        float v = acc[m][n][r];
        if (ccol == clsr[m][r])
          local += (1.0f - v) * inv_B;              // pos: 1 - cos(b, cls[b])
        else if (exs[n])
          local += fmaxf(v - 0.7f, 0.f) * inv_neg;  // relu(M_NEG - (1 - cos))
      }
    }

#pragma unroll
  for (int o = 32; o > 0; o >>= 1) local += __shfl_xor(local, o);
  if (lane == 0) red[w] = local;
  __syncthreads();
  if (tid == 0) {
    float t = 0.f;
#pragma unroll
    for (int i = 0; i < 8; ++i) t += red[i];
    atomicAdd(out, t);
  }
}

extern "C" void kernel_launch(void* const* d_in, const int* in_sizes, int n_in,
                              void* d_out, int out_size, void* d_ws, size_t ws_size,
                              hipStream_t stream) {
  const float* preds  = (const float*)d_in[0];
  const float* labels = (const float*)d_in[1];
  float* out = (float*)d_out;

  char* ws = (char*)d_ws;
  int*            cnt     = (int*)(ws + 0);
  int*            Ecnt    = (int*)(ws + 8192);
  int*            cls     = (int*)(ws + 8256);
  int*            rowlist = (int*)(ws + 73792);
  int*            exists  = (int*)(ws + 598080);
  unsigned short* pn      = (unsigned short*)(ws + 606272);
  unsigned short* cn      = (unsigned short*)(ws + 8994880);

  hipMemsetAsync(ws, 0, 8256, stream);                 // cnt + Ecnt
  // k_scan launched TWICE deliberately (round-5 timing instrument; see note).
  k_scan<<<2048, 256, 0, stream>>>(labels, cls, cnt, rowlist, out);
  k_scan<<<2048, 256, 0, stream>>>(labels, cls, cnt, rowlist, out);
  k_pn<<<4096, 256, 0, stream>>>(preds, pn);
  k_cn<<<CC, 256, 0, stream>>>(preds, cnt, rowlist, cn, exists, Ecnt);
  k_loss<<<512, 512, 0, stream>>>(pn, cn, cls, exists, Ecnt, out);
}

// Round 6
// 121.026 us; speedup vs baseline: 1.0073x; 1.0073x over previous
//
#include <hip/hip_runtime.h>
#include <hip/hip_bf16.h>

// Problem constants (match reference)
constexpr int BB = 16384;   // batch
constexpr int CC = 2048;    // classes
constexpr int DD = 256;     // dim
constexpr float THR   = 0.8f;
constexpr float EPSN  = 1e-8f;

typedef __bf16 bf16x8 __attribute__((ext_vector_type(8)));
typedef float  f32x4  __attribute__((ext_vector_type(4)));

// ---------------- workspace layout (bytes) ----------------
// [0)         cnt     : C*4   = 8,192      (zeroed each launch)
// [8,192)     Ecnt    : 4 (pad to 8,256)   (zeroed)
// [8,256)     cls     : B*4   = 65,536
// [73,792)    rowlist : C*64*4 = 524,288   (slot-guarded, no zero needed)
// [598,080)   exists  : C*4   = 8,192
// [606,272)   pn      : B*D*2 = 8,388,608  (bf16)
// [8,994,880) cn      : C*D*2 = 1,048,576  (bf16)
constexpr int ROWSLOTS = 64;

// Fat kernel (r4 config): blocks [0,2048) stream labels -> cls/cnt/rowlist
// (+ out=0); blocks [2048,6144) normalize preds -> pn (bf16), 1 wave/row.
__global__ __launch_bounds__(256) void k_prep(const float* __restrict__ labels,
                                              const float* __restrict__ preds,
                                              int* __restrict__ cls,
                                              int* __restrict__ cnt,
                                              int* __restrict__ rowlist,
                                              unsigned short* __restrict__ pn,
                                              float* __restrict__ out) {
  if (blockIdx.x < 2048) {
    if (blockIdx.x == 0 && threadIdx.x == 0) *out = 0.f;
    constexpr size_t total = (size_t)BB * CC / 4;
    size_t q = (size_t)blockIdx.x * 256 + threadIdx.x;
    const float4* l4 = reinterpret_cast<const float4*>(labels);
    for (; q < total; q += 2048 * 256) {
      float4 v = l4[q];
      if (v.x >= THR || v.y >= THR || v.z >= THR || v.w >= THR) {
        int f = (int)(q * 4);
        int row = f >> 11;      // / CC
        int col = f & (CC - 1);
        int c = col + (v.x >= THR ? 0 : v.y >= THR ? 1 : v.z >= THR ? 2 : 3);
        cls[row] = c;
        int s = atomicAdd(&cnt[c], 1);
        if (s < ROWSLOTS) rowlist[c * ROWSLOTS + s] = row;
      }
    }
  } else {
    int b = (blockIdx.x - 2048) * 4 + (threadIdx.x >> 6);
    int lane = threadIdx.x & 63;
    float4 v = reinterpret_cast<const float4*>(preds + (size_t)b * DD)[lane];
    float s = v.x * v.x + v.y * v.y + v.z * v.z + v.w * v.w;
#pragma unroll
    for (int o = 32; o > 0; o >>= 1) s += __shfl_xor(s, o);
    float inv = 1.0f / fmaxf(sqrtf(s), EPSN);
    union { ushort4 u4; unsigned short us[4]; } o;
    float f0 = v.x * inv, f1 = v.y * inv, f2 = v.z * inv, f3 = v.w * inv;
    __bf16 h0 = (__bf16)f0, h1 = (__bf16)f1, h2 = (__bf16)f2, h3 = (__bf16)f3;
    o.us[0] = *reinterpret_cast<unsigned short*>(&h0);
    o.us[1] = *reinterpret_cast<unsigned short*>(&h1);
    o.us[2] = *reinterpret_cast<unsigned short*>(&h2);
    o.us[3] = *reinterpret_cast<unsigned short*>(&h3);
    reinterpret_cast<ushort4*>(pn + (size_t)b * DD)[lane] = o.u4;
  }
}

// Per-class: gather rows via rowlist, mean, normalize -> cn bf16 + exists/Ecnt.
__global__ __launch_bounds__(256) void k_cn(
    const float* __restrict__ preds, const int* __restrict__ cnt,
    const int* __restrict__ rowlist, unsigned short* __restrict__ cn,
    int* __restrict__ exists, int* __restrict__ Ecnt) {
  int c = blockIdx.x;
  int t = threadIdx.x;
  int n = cnt[c];
  int nn = n < ROWSLOTS ? n : ROWSLOTS;
  float sum = 0.f;
  for (int i = 0; i < nn; ++i) {
    int row = rowlist[c * ROWSLOTS + i];
    sum += preds[(size_t)row * DD + t];
  }
  float mean = sum / (float)(n > 0 ? n : 1);
  float s = mean * mean;
#pragma unroll
  for (int o = 32; o > 0; o >>= 1) s += __shfl_xor(s, o);
  __shared__ float red[4];
  int wave = t >> 6, lane = t & 63;
  if (lane == 0) red[wave] = s;
  __syncthreads();
  float tot = red[0] + red[1] + red[2] + red[3];
  float inv = 1.0f / fmaxf(sqrtf(tot), EPSN);
  __bf16 h = (__bf16)(mean * inv);
  cn[c * DD + t] = *reinterpret_cast<unsigned short*>(&h);
  if (t == 0) {
    exists[c] = (n > 0) ? 1 : 0;
    if (n > 0) atomicAdd(Ecnt, 1);
  }
}

// ---- k_loss: EXACT r4 structure (256x256 tile, BK=64, 8 waves, dbuf 128KB,
// one __syncthreads per step) but the K-sweep runs 3x (12 linearized steps,
// step s -> ks = s%4). acc accumulates 3*cos; epilogue scales by 1/3
// (error ~1e-6 << 1.3e-2 threshold).
// ROUND-6 INSTRUMENT: dur(k_loss_3x) ~= 3*L pushes k_loss above the 74us
// poison-fill floor so its PMC row surfaces; Total - Total_r4 = 2L.
// Swizzle (rule #21, both-sides): element (row,kb) at byte
// row*128 + (kb ^ ((row&7)<<4)); gload_lds dest linear, SOURCE inverse-
// permuted, ds_read same XOR.

__device__ __forceinline__ void stage32k(char* lds, const char* gsrc_row0,
                                         int tid, int ksbyte) {
#pragma unroll
  for (int i = 0; i < 4; ++i) {
    int L = i * 8192 + tid * 16;             // linear LDS byte (32KB / 512thr)
    int row = L >> 7;                        // 128B per row (64 k * 2B)
    int kb  = (L & 127) ^ ((row & 7) << 4);  // involution
    const char* g = gsrc_row0 + (size_t)row * (DD * 2) + ksbyte + kb;
    __builtin_amdgcn_global_load_lds(
        (const __attribute__((address_space(1))) unsigned int*)g,
        (__attribute__((address_space(3))) unsigned int*)(lds + L), 16, 0, 0);
  }
}

__device__ __forceinline__ bf16x8 ldfrag(const char* buf, int row, int kb) {
  return *reinterpret_cast<const bf16x8*>(buf + row * 128 + (kb ^ ((row & 7) << 4)));
}

__global__ __launch_bounds__(512, 2) void k_loss(
    const unsigned short* __restrict__ pn, const unsigned short* __restrict__ cn,
    const int* __restrict__ cls, const int* __restrict__ exists,
    const int* __restrict__ Ecnt, float* __restrict__ out) {
  constexpr int BM = 256, BN = 256;
  __shared__ __align__(16) char sA[2][BM * 64 * 2];   // 2 x 32KB
  __shared__ __align__(16) char sB[2][BN * 64 * 2];   // 2 x 32KB
  __shared__ float red[8];

  // 512 blocks = 64 mtiles x 8 ntiles; bijective XCD swizzle (512 % 8 == 0).
  int bid = blockIdx.x;
  int nb = (bid & 7) * 64 + (bid >> 3);
  int mtile = nb & 63;
  int ntile = nb >> 6;
  int rowbase = mtile * BM, colbase = ntile * BN;
  int tid = threadIdx.x, w = tid >> 6, lane = tid & 63;
  int wm = w >> 2, wn = w & 3;            // wave grid 2 x 4
  int r16 = lane & 15, khi = lane >> 4;   // khi in 0..3
  int arow0 = wm * 128 + r16;             // LDS-A row base for a-frags
  int brow0 = wn * 64 + r16;              // LDS-B row base for b-frags

  const char* pnB = (const char*)pn + (size_t)rowbase * (DD * 2);
  const char* cnB = (const char*)cn + (size_t)colbase * (DD * 2);

  f32x4 acc[8][4];
#pragma unroll
  for (int m = 0; m < 8; ++m)
#pragma unroll
    for (int n = 0; n < 4; ++n) acc[m][n] = {0.f, 0.f, 0.f, 0.f};

  stage32k(sA[0], pnB, tid, 0);
  stage32k(sB[0], cnB, tid, 0);
  __syncthreads();

  int cur = 0;
#pragma unroll
  for (int s = 0; s < 12; ++s) {          // 3 reps x 4 K-steps, linearized
    if (s < 11) {                         // stage step s+1 into other buffer
      int nxt = ((s + 1) & 3) * 128;      // K-byte offset of next step
      stage32k(sA[cur ^ 1], pnB, tid, nxt);
      stage32k(sB[cur ^ 1], cnB, tid, nxt);
    }
    const char* bufA = sA[cur];
    const char* bufB = sB[cur];
#pragma unroll
    for (int kk = 0; kk < 2; ++kk) {      // 2 x K=32 per BK=64
      int kb = kk * 64 + khi * 16;
      bf16x8 b[4];
#pragma unroll
      for (int n = 0; n < 4; ++n) b[n] = ldfrag(bufB, brow0 + n * 16, kb);
#pragma unroll
      for (int m = 0; m < 8; ++m) {
        bf16x8 a = ldfrag(bufA, arow0 + m * 16, kb);
#pragma unroll
        for (int n = 0; n < 4; ++n)
          acc[m][n] = __builtin_amdgcn_mfma_f32_16x16x32_bf16(a, b[n], acc[m][n], 0, 0, 0);
      }
    }
    __syncthreads();                      // staged loads landed + reads retired
    cur ^= 1;
  }

  // Epilogue: v = acc/3 (3 reps), then pos (diagonal) + hinge neg -> atomic.
  // D layout: col = lane&15, row = (lane>>4)*4 + reg  (m89-verified)
  constexpr float THIRD = 1.0f / 3.0f;
  int E = *Ecnt;
  float inv_B = 1.0f / (float)BB;
  float inv_neg = inv_B / (float)((E - 1) > 0 ? (E - 1) : 1);
  int grow0 = rowbase + wm * 128;

  int clsr[8][4];
#pragma unroll
  for (int m = 0; m < 8; ++m)
#pragma unroll
    for (int r = 0; r < 4; ++r) clsr[m][r] = cls[grow0 + m * 16 + khi * 4 + r];
  int exs[4];
#pragma unroll
  for (int n = 0; n < 4; ++n) exs[n] = exists[colbase + wn * 64 + n * 16 + r16];

  float local = 0.f;
#pragma unroll
  for (int m = 0; m < 8; ++m)
#pragma unroll
    for (int n = 0; n < 4; ++n) {
      int ccol = colbase + wn * 64 + n * 16 + r16;
#pragma unroll
      for (int r = 0; r < 4; ++r) {
        float v = acc[m][n][r] * THIRD;
        if (ccol == clsr[m][r])
          local += (1.0f - v) * inv_B;              // pos: 1 - cos(b, cls[b])
        else if (exs[n])
          local += fmaxf(v - 0.7f, 0.f) * inv_neg;  // relu(M_NEG - (1 - cos))
      }
    }

#pragma unroll
  for (int o = 32; o > 0; o >>= 1) local += __shfl_xor(local, o);
  if (lane == 0) red[w] = local;
  __syncthreads();
  if (tid == 0) {
    float t = 0.f;
#pragma unroll
    for (int i = 0; i < 8; ++i) t += red[i];
    atomicAdd(out, t);
  }
}

extern "C" void kernel_launch(void* const* d_in, const int* in_sizes, int n_in,
                              void* d_out, int out_size, void* d_ws, size_t ws_size,
                              hipStream_t stream) {
  const float* preds  = (const float*)d_in[0];
  const float* labels = (const float*)d_in[1];
  float* out = (float*)d_out;

  char* ws = (char*)d_ws;
  int*            cnt     = (int*)(ws + 0);
  int*            Ecnt    = (int*)(ws + 8192);
  int*            cls     = (int*)(ws + 8256);
  int*            rowlist = (int*)(ws + 73792);
  int*            exists  = (int*)(ws + 598080);
  unsigned short* pn      = (unsigned short*)(ws + 606272);
  unsigned short* cn      = (unsigned short*)(ws + 8994880);

  hipMemsetAsync(ws, 0, 8256, stream);                 // cnt + Ecnt
  k_prep<<<6144, 256, 0, stream>>>(labels, preds, cls, cnt, rowlist, pn, out);
  k_cn<<<CC, 256, 0, stream>>>(preds, cnt, rowlist, cn, exists, Ecnt);
  k_loss<<<512, 512, 0, stream>>>(pn, cn, cls, exists, Ecnt, out);
}